// Round 1
// baseline (2202.707 us; speedup 1.0000x reference)
//
#include <hip/hip_runtime.h>
#include <cstdint>
#include <cstddef>

#define CIN   256
#define COUT  256
#define CMID  64
#define H     64
#define W     64
#define HO    128
#define WO    128
#define BATCH 4

// ---------------------------------------------------------------------------
// Kernel 1: x2T[b][y][cm][x] = sum_ci inx[b,ci,y,x] * w1[cm,ci] + b1[cm]
// One block per (b, y). Stage the full [256 ci][64 x] fp32 slice in LDS (64 KiB),
// each thread computes a 4cm x 4x register tile.
// ---------------------------------------------------------------------------
__global__ __launch_bounds__(256) void k_x2(const float* __restrict__ inx,
                                            const float* __restrict__ w1,
                                            const float* __restrict__ b1,
                                            float* __restrict__ x2T) {
    __shared__ float sx[CIN * W];      // 65536 B: [ci][x]
    const int b = blockIdx.x >> 6;
    const int y = blockIdx.x & 63;
    const int t = threadIdx.x;

    const float* src = inx + (size_t)b * CIN * H * W + (size_t)y * W;
    #pragma unroll
    for (int i = 0; i < (CIN * W) / 256; ++i) {
        int idx = i * 256 + t;
        int ci = idx >> 6, x = idx & 63;
        sx[idx] = src[(size_t)ci * (H * W) + x];
    }
    __syncthreads();

    const int tx = t & 15, tc = t >> 4;
    const int x0 = tx * 4, cm0 = tc * 4;

    float acc[4][4];
    #pragma unroll
    for (int c = 0; c < 4; ++c) {
        float bb = b1[cm0 + c];
        #pragma unroll
        for (int j = 0; j < 4; ++j) acc[c][j] = bb;
    }

    for (int ci = 0; ci < CIN; ci += 4) {
        float xsv[4][4];
        #pragma unroll
        for (int q = 0; q < 4; ++q) {
            float4 v = *(const float4*)&sx[(ci + q) * W + x0];
            xsv[q][0] = v.x; xsv[q][1] = v.y; xsv[q][2] = v.z; xsv[q][3] = v.w;
        }
        #pragma unroll
        for (int c = 0; c < 4; ++c) {
            float4 wv = *(const float4*)&w1[(size_t)(cm0 + c) * CIN + ci];
            float wq[4] = {wv.x, wv.y, wv.z, wv.w};
            #pragma unroll
            for (int q = 0; q < 4; ++q)
                #pragma unroll
                for (int j = 0; j < 4; ++j)
                    acc[c][j] += wq[q] * xsv[q][j];
        }
    }

    #pragma unroll
    for (int c = 0; c < 4; ++c) {
        float4 v = make_float4(acc[c][0], acc[c][1], acc[c][2], acc[c][3]);
        *(float4*)&x2T[(((size_t)b * H + y) * CMID + (cm0 + c)) * W + x0] = v;
    }
}

// ---------------------------------------------------------------------------
// Kernel 2: fused dual-branch transposed conv + mask combine.
// Block = (b, oy, co tile of 64). Computes all 128 ox for both branches.
// Transposed-conv tap structure (stride 2, k=3, pad 1):
//   oy even -> input row oy/2 with ky=1
//   oy odd  -> rows (oy-1)/2 (ky=2) and (oy+1)/2 (ky=0, skipped if ==H)
//   ox = 2x   -> xs[x]*w[ky][1]
//   ox = 2x+1 -> xs[x]*w[ky][2] + xs[x+1]*w[ky][0]
// Thread tile: 4 co x 8 ox. High result parked in LDS `res` so the 32 fp32
// accumulators are reused for the low branch.
// ---------------------------------------------------------------------------
__global__ __launch_bounds__(256) void k_main(const float* __restrict__ inx,
                                              const float* __restrict__ x2T,
                                              const float* __restrict__ wH,
                                              const float* __restrict__ bH,
                                              const float* __restrict__ wL,
                                              const float* __restrict__ bL,
                                              const float* __restrict__ mask,
                                              float* __restrict__ out) {
    __shared__ float sx[32 * 2 * 68];   // 17408 B: [ci][r][68], x=64..67 zero pad
    __shared__ float res[64 * 132];     // 33792 B: high-branch result [co_l][ox]

    const int t = threadIdx.x;
    const int blk = blockIdx.x;
    const int co_blk = blk & 3;
    const int oy = (blk >> 2) & 127;
    const int b = blk >> 9;
    const int co0 = co_blk * 64;

    int rows[2], kys[2], nrows;
    if ((oy & 1) == 0) {
        rows[0] = oy >> 1; rows[1] = -1; kys[0] = 1; kys[1] = 1; nrows = 1;
    } else {
        rows[0] = (oy - 1) >> 1;
        rows[1] = (oy + 1) >> 1;
        if (rows[1] >= H) rows[1] = -1;   // oy==127: zero-filled row
        kys[0] = 2; kys[1] = 0; nrows = 2;
    }

    const int tx = t & 15, tc = t >> 4;
    const int ox0 = tx * 8;      // 8 output columns
    const int col0 = tc * 4;     // 4 local output channels
    const int xin0 = tx * 4;     // input-x base: outputs [ox0,ox0+8) need x in [xin0, xin0+4]

    float acc[4][8];

    auto zero_acc = [&]() {
        #pragma unroll
        for (int c = 0; c < 4; ++c)
            #pragma unroll
            for (int j = 0; j < 8; ++j) acc[c][j] = 0.f;
    };

    // Generic branch: xbase + ci*ciStride + row*rowStride + x ; weights wgt[(ci*COUT+co)*9 + ky*3 + kx]
    auto process = [&](const float* __restrict__ xbase, int ciStride, int rowStride,
                       const float* __restrict__ wgt, int Ktot) {
        for (int ck = 0; ck < Ktot; ck += 32) {
            __syncthreads();
            #pragma unroll
            for (int i = 0; i < 17; ++i) {              // 32ci * 2r * 68x = 4352 = 17*256
                int slot = i * 256 + t;
                int x = slot % 68;
                int rest = slot / 68;
                int r = rest & 1;
                int ci = rest >> 1;
                int row = rows[r];
                float v = 0.f;
                if (x < W && row >= 0)
                    v = xbase[(size_t)(ck + ci) * ciStride + (size_t)row * rowStride + x];
                sx[(ci * 2 + r) * 68 + x] = v;
            }
            __syncthreads();

            for (int ci = 0; ci < 32; ++ci) {
                for (int r = 0; r < nrows; ++r) {
                    const float* xp = &sx[(ci * 2 + r) * 68 + xin0];
                    float xs0 = xp[0], xs1 = xp[1], xs2 = xp[2], xs3 = xp[3], xs4 = xp[4];
                    const float* wp = wgt + ((size_t)(ck + ci) * COUT + co0 + col0) * 9 + kys[r] * 3;
                    #pragma unroll
                    for (int c = 0; c < 4; ++c) {
                        float w0 = wp[c * 9 + 0], w1v = wp[c * 9 + 1], w2v = wp[c * 9 + 2];
                        acc[c][0] += xs0 * w1v;
                        acc[c][1] += xs0 * w2v + xs1 * w0;
                        acc[c][2] += xs1 * w1v;
                        acc[c][3] += xs1 * w2v + xs2 * w0;
                        acc[c][4] += xs2 * w1v;
                        acc[c][5] += xs2 * w2v + xs3 * w0;
                        acc[c][6] += xs3 * w1v;
                        acc[c][7] += xs3 * w2v + xs4 * w0;
                    }
                }
            }
        }
    };

    // ---- high branch: inx [b][ci][y][x], ciStride = H*W, rowStride = W ----
    zero_acc();
    process(inx + (size_t)b * CIN * H * W, H * W, W, wH, CIN);

    // mask row (inv_mask == 1 - mask exactly; mask is 0/1)
    float mv[8];
    {
        const float* mrow = mask + ((size_t)b * HO + oy) * WO + ox0;
        #pragma unroll
        for (int j = 0; j < 8; ++j) mv[j] = mrow[j];
    }

    // park masked high result in LDS
    #pragma unroll
    for (int c = 0; c < 4; ++c) {
        float bb = bH[co0 + col0 + c];
        #pragma unroll
        for (int j = 0; j < 8; ++j)
            res[(col0 + c) * 132 + ox0 + j] = mv[j] * (acc[c][j] + bb);
    }

    // ---- low branch: x2T [b][y][cm][x], ciStride = W, rowStride = CMID*W ----
    zero_acc();
    process(x2T + (size_t)b * H * CMID * W, W, CMID * W, wL, CMID);

    __syncthreads();   // res writes + last low-chunk compute complete

    #pragma unroll
    for (int c = 0; c < 4; ++c) {
        float bb = bL[co0 + col0 + c];
        float* orow = out + (((size_t)b * COUT + co0 + col0 + c) * HO + oy) * WO + ox0;
        #pragma unroll
        for (int j = 0; j < 8; ++j) {
            float lo = (1.f - mv[j]) * (acc[c][j] + bb);
            orow[j] = res[(col0 + c) * 132 + ox0 + j] + lo;
        }
    }
}

// ---------------------------------------------------------------------------
extern "C" void kernel_launch(void* const* d_in, const int* in_sizes, int n_in,
                              void* d_out, int out_size, void* d_ws, size_t ws_size,
                              hipStream_t stream) {
    const float* inx    = (const float*)d_in[0];
    const float* mask   = (const float*)d_in[1];
    // d_in[2] = inv_mask (unused: mask is binary, inv = 1-mask exactly)
    const float* w_high = (const float*)d_in[3];
    const float* b_high = (const float*)d_in[4];
    const float* w_low1 = (const float*)d_in[5];
    const float* b_low1 = (const float*)d_in[6];
    const float* w_low2 = (const float*)d_in[7];
    const float* b_low2 = (const float*)d_in[8];
    float* out = (float*)d_out;

    float* x2T = (float*)d_ws;   // [B][H][CMID][W] fp32 = 4 MiB

    k_x2<<<BATCH * H, 256, 0, stream>>>(inx, w_low1, b_low1, x2T);
    k_main<<<BATCH * HO * (COUT / 64), 256, 0, stream>>>(inx, x2T, w_high, b_high,
                                                         w_low2, b_low2, mask, out);
}

// Round 2
// 287.000 us; speedup vs baseline: 7.6749x; 7.6749x over previous
//
#include <hip/hip_runtime.h>
#include <cstdint>
#include <cstddef>

#define CIN   256
#define COUT  256
#define CMID  64
#define H     64
#define W     64
#define HO    128
#define WO    128
#define BATCH 4

typedef unsigned short u16;
typedef __attribute__((ext_vector_type(8))) __bf16 bf16x8;
typedef __attribute__((ext_vector_type(4))) float f32x4;

// Guarded bf16 layouts: index 64 in y and x is a zero guard so boundary taps
// (row y+1==64, col x+1==64 -> output_padding edge) need no branches.
#define XT_Y   (H + 1)              // 65
#define XT_X   (W + 1)              // 65
#define XT_YSTR (XT_X * CIN)        // 16640
#define XT_BSTR (XT_Y * XT_YSTR)
#define X2_YSTR (XT_X * CMID)       // 4160
#define X2_BSTR (XT_Y * X2_YSTR)

__device__ __forceinline__ u16 f2bf(float f) {
    unsigned int u = __builtin_bit_cast(unsigned int, f);
    u += 0x7fffu + ((u >> 16) & 1u);          // RNE
    return (u16)(u >> 16);
}

// ---------------------------------------------------------------------------
// Weight pack: WTH[t][co][ci] (bf16), WTL[t][co][cm], W1b[cm][ci]
// wH: [ci][co][3][3], wL: [cm][co][3][3], w1: [cm][ci]
// ---------------------------------------------------------------------------
__global__ __launch_bounds__(256) void k_pack_w(const float* __restrict__ wH,
                                                const float* __restrict__ wL,
                                                const float* __restrict__ w1,
                                                u16* __restrict__ WTH,
                                                u16* __restrict__ WTL,
                                                u16* __restrict__ W1b) {
    const int co = blockIdx.x;
    const int tid = threadIdx.x;
    {
        const int ci = tid;
        const float* src = wH + ((size_t)ci * COUT + co) * 9;
        #pragma unroll
        for (int t = 0; t < 9; ++t)
            WTH[((size_t)t * COUT + co) * CIN + ci] = f2bf(src[t]);
    }
    if (tid < CMID) {
        const int cm = tid;
        const float* src = wL + ((size_t)cm * COUT + co) * 9;
        #pragma unroll
        for (int t = 0; t < 9; ++t)
            WTL[((size_t)t * COUT + co) * CMID + cm] = f2bf(src[t]);
    }
    if (co < CMID)
        W1b[(size_t)co * CIN + tid] = f2bf(w1[(size_t)co * CIN + tid]);
}

// ---------------------------------------------------------------------------
// Input transpose+convert: Xt[b][y][x][ci] bf16, y/x in [0,64], guards zeroed.
// Block (b,y). Thread = ci, reads its contiguous input row, writes transposed.
// ---------------------------------------------------------------------------
__global__ __launch_bounds__(256) void k_xt(const float* __restrict__ inx,
                                            u16* __restrict__ Xt) {
    const int b = blockIdx.x / XT_Y;
    const int y = blockIdx.x % XT_Y;
    const int tid = threadIdx.x;
    u16* dst = Xt + (size_t)b * XT_BSTR + (size_t)y * XT_YSTR;
    if (y == H) {                         // zero guard row
        unsigned int* d32 = (unsigned int*)dst;
        for (int i = tid; i < XT_YSTR / 2; i += 256) d32[i] = 0u;
        return;
    }
    const float* src = inx + (((size_t)b * CIN + tid) * H + y) * W;
    float v[W];
    #pragma unroll
    for (int i = 0; i < W / 4; ++i) {
        float4 t4 = ((const float4*)src)[i];
        v[4 * i + 0] = t4.x; v[4 * i + 1] = t4.y;
        v[4 * i + 2] = t4.z; v[4 * i + 3] = t4.w;
    }
    #pragma unroll
    for (int x = 0; x < W; ++x)
        dst[(size_t)x * CIN + tid] = f2bf(v[x]);
    dst[(size_t)W * CIN + tid] = 0;       // zero guard col
}

// ---------------------------------------------------------------------------
// Bottleneck 1x1: X2t[b][y][x][cm] = bf16( sum_ci W1[cm][ci]*Xt[...] + b1 )
// MFMA: per block (b,y): M=64(cm) x N=64(x) x K=256. Wave w -> 16-cm tile.
// ---------------------------------------------------------------------------
__global__ __launch_bounds__(256) void k_x2t(const u16* __restrict__ Xt,
                                             const u16* __restrict__ W1b,
                                             const float* __restrict__ b1,
                                             u16* __restrict__ X2t) {
    const int b = blockIdx.x / XT_Y;
    const int y = blockIdx.x % XT_Y;
    const int tid = threadIdx.x;
    u16* dst = X2t + (size_t)b * X2_BSTR + (size_t)y * X2_YSTR;
    if (y == H) {                         // zero guard row
        unsigned int* d32 = (unsigned int*)dst;
        for (int i = tid; i < X2_YSTR / 2; i += 256) d32[i] = 0u;
        return;
    }
    const int wv = tid >> 6, lane = tid & 63, l15 = lane & 15, q = lane >> 4;
    const int cm0 = wv * 16;
    f32x4 acc[4] = {};
    const u16* A  = W1b + (size_t)(cm0 + l15) * CIN + q * 8;
    const u16* Bb = Xt + (size_t)b * XT_BSTR + (size_t)y * XT_YSTR
                       + (size_t)l15 * CIN + q * 8;
    #pragma unroll
    for (int kc = 0; kc < CIN; kc += 32) {
        bf16x8 af = *(const bf16x8*)(A + kc);
        #pragma unroll
        for (int n = 0; n < 4; ++n) {
            bf16x8 bfr = *(const bf16x8*)(Bb + (size_t)(n * 16) * CIN + kc);
            acc[n] = __builtin_amdgcn_mfma_f32_16x16x32_bf16(af, bfr, acc[n], 0, 0, 0);
        }
    }
    #pragma unroll
    for (int n = 0; n < 4; ++n) {
        const int x = n * 16 + l15;
        u16 pk[4];
        #pragma unroll
        for (int r = 0; r < 4; ++r)
            pk[r] = f2bf(acc[n][r] + b1[cm0 + q * 4 + r]);
        *(ushort4*)(dst + (size_t)x * CMID + cm0 + q * 4) =
            make_ushort4(pk[0], pk[1], pk[2], pk[3]);
    }
    if (tid < CMID) dst[(size_t)W * CMID + tid] = 0;   // zero guard col
}

// ---------------------------------------------------------------------------
// Main: phase-decomposed dual-branch tconv as MFMA GEMM, mask folded into B.
// Block = (b, y, phase). C[co=256][x=64], K = 256*taps(high) + 64*taps(low).
// Wave w: co tile of 64 -> 4x4 grid of 16x16 tiles, 16 f32x4 accumulators.
// No LDS, no barriers: frags read straight from packed bf16 global (L1/L2).
// ---------------------------------------------------------------------------
__global__ __launch_bounds__(256, 3) void k_main(const u16* __restrict__ Xt,
                                                 const u16* __restrict__ X2t,
                                                 const u16* __restrict__ WTH,
                                                 const u16* __restrict__ WTL,
                                                 const float* __restrict__ bH,
                                                 const float* __restrict__ bL,
                                                 const float* __restrict__ mask,
                                                 float* __restrict__ out) {
    const int blk = blockIdx.x;
    const int p = blk & 3;                 // phase: py=p>>1, px=p&1
    const int y = (blk >> 2) & 63;
    const int b = blk >> 8;
    const int py = p >> 1, px = p & 1;
    const int oy = 2 * y + py;

    const int tid = threadIdx.x;
    const int wv = tid >> 6, lane = tid & 63, l15 = lane & 15, q = lane >> 4;
    const int co0 = wv * 64;

    f32x4 acc[4][4] = {};

    float mv[4];                           // mask per N-tile column (exact 0/1)
    const float* mrow = mask + (size_t)(b * HO + oy) * WO;
    #pragma unroll
    for (int n = 0; n < 4; ++n) mv[n] = mrow[2 * (16 * n + l15) + px];

    // tap sets: oy parity -> ky/rows, ox parity -> kx/col-shift
    int rrow[2], rky[2], nr, cdx[2], ckx[2], ncx;
    if (py == 0) { rrow[0] = y; rky[0] = 1; nr = 1; }
    else { rrow[0] = y; rky[0] = 2; rrow[1] = y + 1; rky[1] = 0; nr = 2; }
    if (px == 0) { cdx[0] = 0; ckx[0] = 1; ncx = 1; }
    else { cdx[0] = 0; ckx[0] = 2; cdx[1] = 1; ckx[1] = 0; ncx = 2; }

    const bf16x8 z8 = {};

    for (int ri = 0; ri < nr; ++ri) {
        const size_t rb1 = (size_t)b * XT_BSTR + (size_t)rrow[ri] * XT_YSTR;
        const size_t rb2 = (size_t)b * X2_BSTR + (size_t)rrow[ri] * X2_YSTR;
        for (int cj = 0; cj < ncx; ++cj) {
            const int t = rky[ri] * 3 + ckx[cj];
            const int dx = cdx[cj];
            // ---- high branch: K=256, B columns selected where mask==1 ----
            const u16* A = WTH + ((size_t)t * COUT + co0 + l15) * CIN + q * 8;
            const u16* B = Xt + rb1 + (size_t)(dx + l15) * CIN + q * 8;
            #pragma unroll
            for (int kc = 0; kc < CIN; kc += 32) {
                bf16x8 af[4], bfr[4];
                #pragma unroll
                for (int mi = 0; mi < 4; ++mi)
                    af[mi] = *(const bf16x8*)(A + (size_t)mi * 16 * CIN + kc);
                #pragma unroll
                for (int ni = 0; ni < 4; ++ni) {
                    bf16x8 t8 = *(const bf16x8*)(B + (size_t)ni * 16 * CIN + kc);
                    bfr[ni] = (mv[ni] != 0.f) ? t8 : z8;
                }
                #pragma unroll
                for (int mi = 0; mi < 4; ++mi)
                    #pragma unroll
                    for (int ni = 0; ni < 4; ++ni)
                        acc[mi][ni] = __builtin_amdgcn_mfma_f32_16x16x32_bf16(
                            af[mi], bfr[ni], acc[mi][ni], 0, 0, 0);
            }
            // ---- low branch: K=64, B columns selected where mask==0 ----
            const u16* Al = WTL + ((size_t)t * COUT + co0 + l15) * CMID + q * 8;
            const u16* Bl = X2t + rb2 + (size_t)(dx + l15) * CMID + q * 8;
            #pragma unroll
            for (int kc = 0; kc < CMID; kc += 32) {
                bf16x8 af[4], bfr[4];
                #pragma unroll
                for (int mi = 0; mi < 4; ++mi)
                    af[mi] = *(const bf16x8*)(Al + (size_t)mi * 16 * CMID + kc);
                #pragma unroll
                for (int ni = 0; ni < 4; ++ni) {
                    bf16x8 t8 = *(const bf16x8*)(Bl + (size_t)ni * 16 * CMID + kc);
                    bfr[ni] = (mv[ni] == 0.f) ? t8 : z8;
                }
                #pragma unroll
                for (int mi = 0; mi < 4; ++mi)
                    #pragma unroll
                    for (int ni = 0; ni < 4; ++ni)
                        acc[mi][ni] = __builtin_amdgcn_mfma_f32_16x16x32_bf16(
                            af[mi], bfr[ni], acc[mi][ni], 0, 0, 0);
            }
        }
    }

    // Epilogue: out[b][co][oy][2x+px] = acc + (mask ? bH : bL)
    #pragma unroll
    for (int mi = 0; mi < 4; ++mi) {
        float bh[4], bl[4];
        #pragma unroll
        for (int r = 0; r < 4; ++r) {
            const int co = co0 + 16 * mi + q * 4 + r;
            bh[r] = bH[co]; bl[r] = bL[co];
        }
        #pragma unroll
        for (int ni = 0; ni < 4; ++ni) {
            const int x = 16 * ni + l15;
            const int ox = 2 * x + px;
            const float m = mv[ni];
            float* op = out + (((size_t)(b * COUT + co0 + 16 * mi + q * 4)) * HO + oy) * WO + ox;
            #pragma unroll
            for (int r = 0; r < 4; ++r)
                op[(size_t)r * HO * WO] = acc[mi][ni][r] + (m != 0.f ? bh[r] : bl[r]);
        }
    }
}

// ---------------------------------------------------------------------------
extern "C" void kernel_launch(void* const* d_in, const int* in_sizes, int n_in,
                              void* d_out, int out_size, void* d_ws, size_t ws_size,
                              hipStream_t stream) {
    const float* inx    = (const float*)d_in[0];
    const float* mask   = (const float*)d_in[1];
    // d_in[2] = inv_mask (unused: mask is exactly 0/1, inv = 1-mask)
    const float* w_high = (const float*)d_in[3];
    const float* b_high = (const float*)d_in[4];
    const float* w_low1 = (const float*)d_in[5];
    const float* b_low1 = (const float*)d_in[6];
    const float* w_low2 = (const float*)d_in[7];
    const float* b_low2 = (const float*)d_in[8];
    float* out = (float*)d_out;

    char* ws = (char*)d_ws;
    u16* Xt  = (u16*)(ws);                 //  8,652,800 B
    u16* X2t = (u16*)(ws + 8652800);       //  2,163,200 B
    u16* WTH = (u16*)(ws + 10816000);      //  1,179,648 B
    u16* WTL = (u16*)(ws + 11995648);      //    294,912 B
    u16* W1b = (u16*)(ws + 12290560);      //     32,768 B  (total ~11.8 MiB)

    k_pack_w<<<COUT, 256, 0, stream>>>(w_high, w_low2, w_low1, WTH, WTL, W1b);
    k_xt<<<BATCH * XT_Y, 256, 0, stream>>>(inx, Xt);
    k_x2t<<<BATCH * XT_Y, 256, 0, stream>>>(Xt, W1b, b_low1, X2t);
    k_main<<<BATCH * H * 4, 256, 0, stream>>>(Xt, X2t, WTH, WTL,
                                              b_high, b_low2, mask, out);
}

// Round 3
// 188.675 us; speedup vs baseline: 11.6746x; 1.5211x over previous
//
#include <hip/hip_runtime.h>
#include <cstdint>
#include <cstddef>

#define CIN   256
#define COUT  256
#define CMID  64
#define H     64
#define W     64
#define HO    128
#define WO    128
#define BATCH 4

typedef unsigned short u16;
typedef unsigned int   u32;
typedef __attribute__((ext_vector_type(8))) __bf16 bf16x8;
typedef __attribute__((ext_vector_type(4))) float f32x4;

// Fragment-major layouts (granule = 8 bf16 = 16 B, always lane-contiguous):
//   Xt [b][y(65)][kc(8)][q(4)][x(65)][8ci]   row stride 16640 u16 (33280 B)
//   X2t[b][y(65)][kc2(2)][q(4)][x(65)][8cm]  row stride 4160 u16
//   WPH[t(9)][kc(8)][q(4)][co(256)][8ci]
//   WPL[t(9)][kc2(2)][q(4)][co(256)][8cm]
//   W1P[kc(8)][q(4)][cm(64)][8ci]
// y==64 and x==64 are zero guards (row y+1 and col x+1 at boundaries).
#define XT_ROW  16640
#define X2_ROW  4160

__device__ __forceinline__ u16 f2bf(float f) {
    u32 u = __builtin_bit_cast(u32, f);
    u += 0x7fffu + ((u >> 16) & 1u);          // RNE
    return (u16)(u >> 16);
}

// ---------------------------------------------------------------------------
// Weight pack. Grid: 72 blocks = (t 0..8, kc 0..7), 256 threads = co.
// ---------------------------------------------------------------------------
__global__ __launch_bounds__(256) void k_pack_w(const float* __restrict__ wH,
                                                const float* __restrict__ wL,
                                                const float* __restrict__ w1,
                                                u16* __restrict__ WPH,
                                                u16* __restrict__ WPL,
                                                u16* __restrict__ W1P) {
    const int t = blockIdx.x / 8;
    const int kc = blockIdx.x % 8;
    const int co = threadIdx.x;
    #pragma unroll
    for (int q = 0; q < 4; ++q) {
        u16 pk[8];
        #pragma unroll
        for (int j = 0; j < 8; ++j) {
            int ci = kc * 32 + q * 8 + j;
            pk[j] = f2bf(wH[((size_t)ci * COUT + co) * 9 + t]);
        }
        *(ushort4*)(WPH + ((((size_t)t * 8 + kc) * 4 + q) * 256 + co) * 8)     = *(ushort4*)&pk[0];
        *(ushort4*)(WPH + ((((size_t)t * 8 + kc) * 4 + q) * 256 + co) * 8 + 4) = *(ushort4*)&pk[4];
    }
    if (kc < 2) {                                  // WPL (cm = kc*32+q*8+j < 64)
        #pragma unroll
        for (int q = 0; q < 4; ++q) {
            u16 pk[8];
            #pragma unroll
            for (int j = 0; j < 8; ++j) {
                int cm = kc * 32 + q * 8 + j;
                pk[j] = f2bf(wL[((size_t)cm * COUT + co) * 9 + t]);
            }
            *(ushort4*)(WPL + ((((size_t)t * 2 + kc) * 4 + q) * 256 + co) * 8)     = *(ushort4*)&pk[0];
            *(ushort4*)(WPL + ((((size_t)t * 2 + kc) * 4 + q) * 256 + co) * 8 + 4) = *(ushort4*)&pk[4];
        }
    }
    if (t == 0 && co < CMID) {                     // W1P
        #pragma unroll
        for (int q = 0; q < 4; ++q) {
            u16 pk[8];
            #pragma unroll
            for (int j = 0; j < 8; ++j)
                pk[j] = f2bf(w1[(size_t)co * CIN + kc * 32 + q * 8 + j]);
            *(ushort4*)(W1P + (((size_t)kc * 4 + q) * 64 + co) * 8)     = *(ushort4*)&pk[0];
            *(ushort4*)(W1P + (((size_t)kc * 4 + q) * 64 + co) * 8 + 4) = *(ushort4*)&pk[4];
        }
    }
}

// ---------------------------------------------------------------------------
// Input convert to fragment-major. Grid: (b, y 0..64), 256 threads.
// Thread (g0 = t>>6, x = t&63): 8 slice iterations, reads 256B-coalesced rows.
// ---------------------------------------------------------------------------
__global__ __launch_bounds__(256) void k_xt(const float* __restrict__ inx,
                                            u16* __restrict__ Xt) {
    const int b = blockIdx.x / 65;
    const int y = blockIdx.x % 65;
    const int tid = threadIdx.x;
    u16* dst = Xt + (size_t)(b * 65 + y) * XT_ROW;
    if (y == H) {                                  // zero guard row
        u32* d = (u32*)dst;
        for (int i = tid; i < XT_ROW / 2; i += 256) d[i] = 0u;
        return;
    }
    const int x = tid & 63, g0 = tid >> 6;
    #pragma unroll
    for (int gg = 0; gg < 8; ++gg) {
        const int s = gg * 4 + g0;                 // slice 0..31; ci0 = s*8
        u16 pk[8];
        #pragma unroll
        for (int j = 0; j < 8; ++j)
            pk[j] = f2bf(inx[(((size_t)b * CIN + s * 8 + j) * H + y) * W + x]);
        *(ushort4*)(dst + ((size_t)s * 65 + x) * 8)     = *(ushort4*)&pk[0];
        *(ushort4*)(dst + ((size_t)s * 65 + x) * 8 + 4) = *(ushort4*)&pk[4];
    }
    if (tid < 128) {                               // zero guard col x=64
        const int s = tid >> 2;
        ((u32*)(dst + ((size_t)s * 65 + 64) * 8))[tid & 3] = 0u;
    }
}

// ---------------------------------------------------------------------------
// Bottleneck 1x1 (MFMA), writes fragment-major X2t. Grid: (b, y 0..64).
// Wave wv -> x-tile; acc over mi (cm tiles).
// ---------------------------------------------------------------------------
__global__ __launch_bounds__(256) void k_x2t(const u16* __restrict__ Xt,
                                             const u16* __restrict__ W1P,
                                             const float* __restrict__ b1,
                                             u16* __restrict__ X2t) {
    const int b = blockIdx.x / 65;
    const int y = blockIdx.x % 65;
    const int tid = threadIdx.x;
    u16* dst = X2t + (size_t)(b * 65 + y) * X2_ROW;
    if (y == H) {                                  // zero guard row
        u32* d = (u32*)dst;
        for (int i = tid; i < X2_ROW / 2; i += 256) d[i] = 0u;
        return;
    }
    const int wv = tid >> 6, lane = tid & 63, l15 = lane & 15, q = lane >> 4;
    const u16* XR = Xt + (size_t)(b * 65 + y) * XT_ROW;
    f32x4 acc[4] = {};
    #pragma unroll
    for (int kc = 0; kc < 8; ++kc) {
        bf16x8 bfr = *(const bf16x8*)(XR + ((size_t)(kc * 4 + q) * 65 + wv * 16 + l15) * 8);
        #pragma unroll
        for (int mi = 0; mi < 4; ++mi) {
            bf16x8 af = *(const bf16x8*)(W1P + (((size_t)kc * 4 + q) * 64 + mi * 16 + l15) * 8);
            acc[mi] = __builtin_amdgcn_mfma_f32_16x16x32_bf16(af, bfr, acc[mi], 0, 0, 0);
        }
    }
    const int x = wv * 16 + l15;
    #pragma unroll
    for (int mi = 0; mi < 4; ++mi) {
        const int kc2 = mi >> 1;
        const int qq  = ((mi & 1) << 1) | (q >> 1);
        u16 pk[4];
        #pragma unroll
        for (int r = 0; r < 4; ++r)
            pk[r] = f2bf(acc[mi][r] + b1[mi * 16 + q * 4 + r]);
        *(ushort4*)(dst + ((size_t)(kc2 * 4 + qq) * 65 + x) * 8 + (q & 1) * 4) = *(ushort4*)&pk[0];
    }
    if (tid < 32)                                  // zero guard col x=64
        ((u32*)(dst + ((size_t)(tid >> 2) * 65 + 64) * 8))[tid & 3] = 0u;
}

// ---------------------------------------------------------------------------
// Main: px-merged, dual-accumulator, barrier-free MFMA kernel.
// Grid: 2048 = (b, y 0..63, py, coQ). Wave = 16-co tile.
// Even ox: tap kx=1 (dx0). Odd ox: kx=2 (dx0) + kx=0 (dx1).
// Epilogue: float2 (ox,ox+1) stores -> full-density lines.
// ---------------------------------------------------------------------------
__global__ __launch_bounds__(256, 3) void k_main(const u16* __restrict__ Xt,
                                                 const u16* __restrict__ X2t,
                                                 const u16* __restrict__ WPH,
                                                 const u16* __restrict__ WPL,
                                                 const float* __restrict__ bH,
                                                 const float* __restrict__ bL,
                                                 const float* __restrict__ mask,
                                                 float* __restrict__ out) {
    const int blk = blockIdx.x;
    const int coQ = blk & 3;
    const int py = (blk >> 2) & 1;
    const int y = (blk >> 3) & 63;
    const int b = blk >> 9;
    const int oy = 2 * y + py;

    const int tid = threadIdx.x;
    const int wv = tid >> 6, lane = tid & 63, l15 = lane & 15, q = lane >> 4;
    const int co0 = coQ * 64 + wv * 16;

    f32x4 he[4] = {}, ho[4] = {}, le[4] = {}, lo_[4] = {};

    int nr, rrow[2], rky[2];
    if (py == 0) { nr = 1; rrow[0] = y; rky[0] = 1; }
    else { nr = 2; rrow[0] = y; rky[0] = 2; rrow[1] = y + 1; rky[1] = 0; }

    for (int r = 0; r < nr; ++r) {
        const int ky = rky[r];
        // ---- high branch: K=256 over 8 chunks ----
        const u16* XR = Xt + (size_t)(b * 65 + rrow[r]) * XT_ROW;
        #pragma unroll
        for (int kc = 0; kc < 8; ++kc) {
            const u16* Bp = XR + ((size_t)(kc * 4 + q) * 65 + l15) * 8;
            bf16x8 b0[4], b1v[4];
            #pragma unroll
            for (int ni = 0; ni < 4; ++ni) b0[ni]  = *(const bf16x8*)(Bp + ni * 128);
            #pragma unroll
            for (int ni = 0; ni < 4; ++ni) b1v[ni] = *(const bf16x8*)(Bp + ni * 128 + 8);
            const size_t wb = (((size_t)(ky * 3) * 8 + kc) * 4 + q) * 256 + co0 + l15;
            bf16x8 a0 = *(const bf16x8*)(WPH + wb * 8);                    // kx=0
            bf16x8 a1 = *(const bf16x8*)(WPH + (wb + (size_t)1 * 8 * 4 * 256) * 8);  // kx=1
            bf16x8 a2 = *(const bf16x8*)(WPH + (wb + (size_t)2 * 8 * 4 * 256) * 8);  // kx=2
            #pragma unroll
            for (int ni = 0; ni < 4; ++ni)
                he[ni] = __builtin_amdgcn_mfma_f32_16x16x32_bf16(a1, b0[ni], he[ni], 0, 0, 0);
            #pragma unroll
            for (int ni = 0; ni < 4; ++ni)
                ho[ni] = __builtin_amdgcn_mfma_f32_16x16x32_bf16(a2, b0[ni], ho[ni], 0, 0, 0);
            #pragma unroll
            for (int ni = 0; ni < 4; ++ni)
                ho[ni] = __builtin_amdgcn_mfma_f32_16x16x32_bf16(a0, b1v[ni], ho[ni], 0, 0, 0);
        }
        // ---- low branch: K=64 over 2 chunks ----
        const u16* X2R = X2t + (size_t)(b * 65 + rrow[r]) * X2_ROW;
        #pragma unroll
        for (int kc2 = 0; kc2 < 2; ++kc2) {
            const u16* Bp = X2R + ((size_t)(kc2 * 4 + q) * 65 + l15) * 8;
            bf16x8 b0[4], b1v[4];
            #pragma unroll
            for (int ni = 0; ni < 4; ++ni) b0[ni]  = *(const bf16x8*)(Bp + ni * 128);
            #pragma unroll
            for (int ni = 0; ni < 4; ++ni) b1v[ni] = *(const bf16x8*)(Bp + ni * 128 + 8);
            const size_t wb = (((size_t)(ky * 3) * 2 + kc2) * 4 + q) * 256 + co0 + l15;
            bf16x8 a0 = *(const bf16x8*)(WPL + wb * 8);
            bf16x8 a1 = *(const bf16x8*)(WPL + (wb + (size_t)1 * 2 * 4 * 256) * 8);
            bf16x8 a2 = *(const bf16x8*)(WPL + (wb + (size_t)2 * 2 * 4 * 256) * 8);
            #pragma unroll
            for (int ni = 0; ni < 4; ++ni)
                le[ni] = __builtin_amdgcn_mfma_f32_16x16x32_bf16(a1, b0[ni], le[ni], 0, 0, 0);
            #pragma unroll
            for (int ni = 0; ni < 4; ++ni)
                lo_[ni] = __builtin_amdgcn_mfma_f32_16x16x32_bf16(a2, b0[ni], lo_[ni], 0, 0, 0);
            #pragma unroll
            for (int ni = 0; ni < 4; ++ni)
                lo_[ni] = __builtin_amdgcn_mfma_f32_16x16x32_bf16(a0, b1v[ni], lo_[ni], 0, 0, 0);
        }
    }

    // ---- epilogue ----
    float bhv[4], blv[4];
    #pragma unroll
    for (int r = 0; r < 4; ++r) {
        bhv[r] = bH[co0 + q * 4 + r];
        blv[r] = bL[co0 + q * 4 + r];
    }
    const float* mrow = mask + ((size_t)b * HO + oy) * WO;
    #pragma unroll
    for (int ni = 0; ni < 4; ++ni) {
        const int x = 16 * ni + l15;
        float2 mm = *(const float2*)(mrow + 2 * x);
        #pragma unroll
        for (int r = 0; r < 4; ++r) {
            const int co = co0 + q * 4 + r;
            float2 v;
            v.x = (mm.x != 0.f) ? he[ni][r] + bhv[r] : le[ni][r] + blv[r];
            v.y = (mm.y != 0.f) ? ho[ni][r] + bhv[r] : lo_[ni][r] + blv[r];
            *(float2*)(out + (((size_t)b * COUT + co) * HO + oy) * WO + 2 * x) = v;
        }
    }
}

// ---------------------------------------------------------------------------
extern "C" void kernel_launch(void* const* d_in, const int* in_sizes, int n_in,
                              void* d_out, int out_size, void* d_ws, size_t ws_size,
                              hipStream_t stream) {
    const float* inx    = (const float*)d_in[0];
    const float* mask   = (const float*)d_in[1];
    // d_in[2] = inv_mask (unused: mask is exactly 0/1)
    const float* w_high = (const float*)d_in[3];
    const float* b_high = (const float*)d_in[4];
    const float* w_low1 = (const float*)d_in[5];
    const float* b_low1 = (const float*)d_in[6];
    const float* w_low2 = (const float*)d_in[7];
    const float* b_low2 = (const float*)d_in[8];
    float* out = (float*)d_out;

    char* ws = (char*)d_ws;
    u16* Xt  = (u16*)(ws);                 //  8,652,800 B
    u16* X2t = (u16*)(ws + 8652800);       //  2,163,200 B
    u16* WPH = (u16*)(ws + 10816000);      //  1,179,648 B
    u16* WPL = (u16*)(ws + 11995648);      //    294,912 B
    u16* W1P = (u16*)(ws + 12290560);      //     32,768 B

    k_pack_w<<<72, 256, 0, stream>>>(w_high, w_low2, w_low1, WPH, WPL, W1P);
    k_xt<<<BATCH * 65, 256, 0, stream>>>(inx, Xt);
    k_x2t<<<BATCH * 65, 256, 0, stream>>>(Xt, W1P, b_low1, X2t);
    k_main<<<BATCH * 64 * 2 * 4, 256, 0, stream>>>(Xt, X2t, WPH, WPL,
                                                   b_high, b_low2, mask, out);
}

// Round 4
// 133.867 us; speedup vs baseline: 16.4545x; 1.4094x over previous
//
#include <hip/hip_runtime.h>
#include <cstdint>
#include <cstddef>

#define CIN   256
#define COUT  256
#define CMID  64
#define H     64
#define W     64
#define HO    128
#define WO    128
#define BATCH 4

typedef unsigned short u16;
typedef unsigned int   u32;
typedef __attribute__((ext_vector_type(8))) __bf16 bf16x8;
typedef __attribute__((ext_vector_type(4))) float f32x4;

// Packed layouts (granule = 8 bf16 = 16 B, lane-contiguous):
//   Xt [b][y(65)][s=kc*4+q (32)][x(64)][8ci]   row = 16384 u16
//   X2t[b][y(65)][s=kc2*4+q (8)][x(64)][8cm]   row = 4096 u16
//   WPH[t(9)][kc(8)][q(4)][co(256)][8ci]
//   WPL[t(9)][kc2(2)][q(4)][co(256)][8cm]
//   W1P[kc(8)][q(4)][cm(64)][8ci]
// y==64 is a zero guard row. x-guard (x==64) lives only in k_main's LDS.
#define XT_ROW  16384
#define X2_ROW  4096

#define AS1 __attribute__((address_space(1)))
#define AS3 __attribute__((address_space(3)))

// global -> LDS direct 16B copy. LDS dst must be wave-uniform; HW adds lane*16.
// AS3 pointers are 32-bit; generic LDS addr low 32 bits == LDS offset on gfx9+.
__device__ __forceinline__ void g2l16(const void* g, const void* l) {
    __builtin_amdgcn_global_load_lds((const AS1 u32*)(uintptr_t)g,
                                     (AS3 u32*)(u32)(uintptr_t)l, 16, 0, 0);
}

__device__ __forceinline__ u16 f2bf(float f) {
    u32 u = __builtin_bit_cast(u32, f);
    u += 0x7fffu + ((u >> 16) & 1u);          // RNE
    return (u16)(u >> 16);
}

// ---------------------------------------------------------------------------
// Weight pack. Grid: 72 blocks = (t 0..8, kc 0..7), 256 threads = co.
// ---------------------------------------------------------------------------
__global__ __launch_bounds__(256) void k_pack_w(const float* __restrict__ wH,
                                                const float* __restrict__ wL,
                                                const float* __restrict__ w1,
                                                u16* __restrict__ WPH,
                                                u16* __restrict__ WPL,
                                                u16* __restrict__ W1P) {
    const int t = blockIdx.x / 8;
    const int kc = blockIdx.x % 8;
    const int co = threadIdx.x;
    #pragma unroll
    for (int q = 0; q < 4; ++q) {
        u16 pk[8];
        #pragma unroll
        for (int j = 0; j < 8; ++j) {
            int ci = kc * 32 + q * 8 + j;
            pk[j] = f2bf(wH[((size_t)ci * COUT + co) * 9 + t]);
        }
        *(ushort4*)(WPH + ((((size_t)t * 8 + kc) * 4 + q) * 256 + co) * 8)     = *(ushort4*)&pk[0];
        *(ushort4*)(WPH + ((((size_t)t * 8 + kc) * 4 + q) * 256 + co) * 8 + 4) = *(ushort4*)&pk[4];
    }
    if (kc < 2) {
        #pragma unroll
        for (int q = 0; q < 4; ++q) {
            u16 pk[8];
            #pragma unroll
            for (int j = 0; j < 8; ++j) {
                int cm = kc * 32 + q * 8 + j;
                pk[j] = f2bf(wL[((size_t)cm * COUT + co) * 9 + t]);
            }
            *(ushort4*)(WPL + ((((size_t)t * 2 + kc) * 4 + q) * 256 + co) * 8)     = *(ushort4*)&pk[0];
            *(ushort4*)(WPL + ((((size_t)t * 2 + kc) * 4 + q) * 256 + co) * 8 + 4) = *(ushort4*)&pk[4];
        }
    }
    if (t == 0 && co < CMID) {
        #pragma unroll
        for (int q = 0; q < 4; ++q) {
            u16 pk[8];
            #pragma unroll
            for (int j = 0; j < 8; ++j)
                pk[j] = f2bf(w1[(size_t)co * CIN + kc * 32 + q * 8 + j]);
            *(ushort4*)(W1P + (((size_t)kc * 4 + q) * 64 + co) * 8)     = *(ushort4*)&pk[0];
            *(ushort4*)(W1P + (((size_t)kc * 4 + q) * 64 + co) * 8 + 4) = *(ushort4*)&pk[4];
        }
    }
}

// ---------------------------------------------------------------------------
// Fused prep: convert inx row -> (LDS + global Xt), then 1x1 bottleneck MFMA
// from LDS -> X2t. Grid: (b, y 0..64), 256 threads.
// ---------------------------------------------------------------------------
__global__ __launch_bounds__(256) void k_prep(const float* __restrict__ inx,
                                              const u16* __restrict__ W1P,
                                              const float* __restrict__ b1,
                                              u16* __restrict__ Xt,
                                              u16* __restrict__ X2t) {
    __shared__ u16 sX[32 * 64 * 8];               // 32768 B, [s][x][8ci]
    const int b = blockIdx.x / 65;
    const int y = blockIdx.x % 65;
    const int tid = threadIdx.x;
    u16* xrow  = Xt  + (size_t)(b * 65 + y) * XT_ROW;
    u16* x2row = X2t + (size_t)(b * 65 + y) * X2_ROW;
    if (y == H) {                                 // zero guard rows
        uint4 z = {0, 0, 0, 0};
        #pragma unroll
        for (int i = 0; i < 8; ++i) *(uint4*)(xrow + (i * 256 + tid) * 8) = z;
        #pragma unroll
        for (int i = 0; i < 2; ++i) *(uint4*)(x2row + (i * 256 + tid) * 8) = z;
        return;
    }
    const int x = tid & 63, g0 = tid >> 6;
    #pragma unroll
    for (int gg = 0; gg < 8; ++gg) {
        const int s = gg * 4 + g0;                // s = kc*4+q, ci0 = s*8
        u16 pk[8];
        #pragma unroll
        for (int j = 0; j < 8; ++j)
            pk[j] = f2bf(inx[(((size_t)b * CIN + s * 8 + j) * H + y) * W + x]);
        uint4 v = *(uint4*)pk;
        *(uint4*)(xrow + ((size_t)s * 64 + x) * 8) = v;
        *(uint4*)(sX   + ((size_t)s * 64 + x) * 8) = v;
    }
    __syncthreads();
    // 1x1: M=64 cm x N=64 x, K=256. Wave wv -> x tile.
    const int wv = tid >> 6, lane = tid & 63, l15 = lane & 15, q = lane >> 4;
    f32x4 acc[4] = {};
    #pragma unroll
    for (int kc = 0; kc < 8; ++kc) {
        bf16x8 bfr = *(const bf16x8*)(sX + ((size_t)(kc * 4 + q) * 64 + wv * 16 + l15) * 8);
        #pragma unroll
        for (int mi = 0; mi < 4; ++mi) {
            bf16x8 af = *(const bf16x8*)(W1P + (((size_t)kc * 4 + q) * 64 + mi * 16 + l15) * 8);
            acc[mi] = __builtin_amdgcn_mfma_f32_16x16x32_bf16(af, bfr, acc[mi], 0, 0, 0);
        }
    }
    const int xx = wv * 16 + l15;
    #pragma unroll
    for (int mi = 0; mi < 4; ++mi) {
        const int kc2 = mi >> 1;
        const int qq  = ((mi & 1) << 1) | (q >> 1);
        u16 pk[4];
        #pragma unroll
        for (int r = 0; r < 4; ++r)
            pk[r] = f2bf(acc[mi][r] + b1[mi * 16 + q * 4 + r]);
        *(ushort4*)(x2row + ((size_t)(kc2 * 4 + qq) * 64 + xx) * 8 + (q & 1) * 4) = *(ushort4*)&pk[0];
    }
}

// ---------------------------------------------------------------------------
// Main: LDS-staged phase GEMM, column-exclusive accumulation.
// Grid 512 = (py, b, yP 0..31, coH). 4 waves = (rowR, coQ).
// Wave tile: co 64 (mi=4) x x 64 (ni=4) x {even,odd} -> ce/co_ 128 VGPR.
// K-chunks: 8 high (CIN) + 2 low (CMID). Per chunk: global_load_lds stages
// A (nr*3 taps x 128co x k32) + B (nr+1 input rows); both shared across waves.
// Mask folded per column: high chunks keep B where sel==1, low where sel==0.
// ---------------------------------------------------------------------------
__global__ __launch_bounds__(256, 2) void k_main(const u16* __restrict__ Xt,
                                                 const u16* __restrict__ X2t,
                                                 const u16* __restrict__ WPH,
                                                 const u16* __restrict__ WPL,
                                                 const float* __restrict__ bH,
                                                 const float* __restrict__ bL,
                                                 const float* __restrict__ mask,
                                                 float* __restrict__ out) {
    __shared__ u16 sA[2 * 3 * 4 * 128 * 8];       // 49152 B [dy][kx][q][co128][8]
    __shared__ u16 sB[3 * 4 * 65 * 8];            // 12480 B [r][q][x65][8]

    const int blk = blockIdx.x;
    const int coH = blk & 1;
    const int yP  = (blk >> 1) & 31;
    const int b   = (blk >> 6) & 3;
    const int py  = blk >> 8;
    const int y0  = yP * 2;
    const int nr  = py + 1;                       // taps in y: 1 (even oy) / 2 (odd)

    const int tid = threadIdx.x;
    const int wid = tid >> 6, lane = tid & 63, l15 = lane & 15, q = lane >> 4;
    const int rowR = wid >> 1, coQ = wid & 1;
    const int oy = 2 * (y0 + rowR) + py;

    // per-column branch selects (mask is exactly 0/1)
    int selE[4], selO[4];
    const float* mrow = mask + ((size_t)b * HO + oy) * WO;
    #pragma unroll
    for (int ni = 0; ni < 4; ++ni) {
        float2 mm = *(const float2*)(mrow + 2 * (ni * 16 + l15));
        selE[ni] = (mm.x != 0.f);
        selO[ni] = (mm.y != 0.f);
    }

    if (tid < 12) {                               // zero LDS x-guard granules
        uint4 z = {0, 0, 0, 0};
        *(uint4*)(sB + (((tid >> 2) * 4 + (tid & 3)) * 65 + 64) * 8) = z;
    }

    f32x4 ce[4][4] = {}, co_[4][4] = {};

    for (int c = 0; c < 10; ++c) {
        const bool hi = (c < 8);
        const int hiI = hi ? 1 : 0;
        const int kc  = hi ? c : c - 8;
        const int kcn = hi ? 8 : 2;
        const u16* Wp = hi ? WPH : WPL;
        const u16* Xp = hi ? Xt : X2t;
        const size_t rowStr = hi ? XT_ROW : X2_ROW;

        __syncthreads();                          // prior compute done with LDS
        // ---- stage A: nr*24 segs of 64 granules; wave takes s%4==wid ----
        for (int dy = 0; dy < nr; ++dy) {
            const int ky = py ? (dy ? 0 : 2) : 1;
            #pragma unroll
            for (int s = 0; s < 6; ++s) {
                const int seg = s * 4 + wid;
                const int h = seg & 1, qq = (seg >> 1) & 3, kx = seg >> 3;
                const u16* src = Wp + ((((size_t)(ky * 3 + kx) * kcn + kc) * 4 + qq) * 256
                                        + coH * 128 + h * 64 + lane) * 8;
                const u16* dst = sA + ((((size_t)(dy * 3 + kx) * 4 + qq) * 128 + h * 64)) * 8;
                g2l16(src, dst);
            }
        }
        // ---- stage B: (nr+1)*4 segs; wave w stages q=wid of each row ----
        for (int r = 0; r <= nr; ++r) {
            const u16* src = Xp + (size_t)(b * 65 + y0 + r) * rowStr
                                + ((size_t)(kc * 4 + wid) * 64 + lane) * 8;
            const u16* dst = sB + ((size_t)(r * 4 + wid) * 65) * 8;
            g2l16(src, dst);
        }
        __syncthreads();                          // staging visible

        // ---- compute ----
        for (int dy = 0; dy < nr; ++dy) {
            const int rB = rowR + dy;
            const u16* bp = sB + (((size_t)(rB * 4 + q)) * 65 + l15) * 8;
            bf16x8 b0[4], b1[4];
            #pragma unroll
            for (int ni = 0; ni < 4; ++ni) {
                b0[ni] = *(const bf16x8*)(bp + (size_t)ni * 16 * 8);
                b1[ni] = *(const bf16x8*)(bp + ((size_t)ni * 16 + 1) * 8);
            }
            const bf16x8 z8 = {};
            bf16x8 be[4], bo0[4], bo1[4];
            #pragma unroll
            for (int ni = 0; ni < 4; ++ni) {
                be[ni]  = (selE[ni] == hiI) ? b0[ni] : z8;
                bo0[ni] = (selO[ni] == hiI) ? b0[ni] : z8;
                bo1[ni] = (selO[ni] == hiI) ? b1[ni] : z8;
            }
            const u16* ap = sA + ((size_t)dy * 1536 + q * 128 + coQ * 64 + l15) * 8;
            bf16x8 a[4];
            // kx=1 -> even cols (ce)
            #pragma unroll
            for (int mi = 0; mi < 4; ++mi) a[mi] = *(const bf16x8*)(ap + ((size_t)1 * 512 + mi * 16) * 8);
            #pragma unroll
            for (int mi = 0; mi < 4; ++mi)
                #pragma unroll
                for (int ni = 0; ni < 4; ++ni)
                    ce[mi][ni] = __builtin_amdgcn_mfma_f32_16x16x32_bf16(a[mi], be[ni], ce[mi][ni], 0, 0, 0);
            // kx=2 -> odd cols, dx=0 (co_)
            #pragma unroll
            for (int mi = 0; mi < 4; ++mi) a[mi] = *(const bf16x8*)(ap + ((size_t)2 * 512 + mi * 16) * 8);
            #pragma unroll
            for (int mi = 0; mi < 4; ++mi)
                #pragma unroll
                for (int ni = 0; ni < 4; ++ni)
                    co_[mi][ni] = __builtin_amdgcn_mfma_f32_16x16x32_bf16(a[mi], bo0[ni], co_[mi][ni], 0, 0, 0);
            // kx=0 -> odd cols, dx=1 (co_)
            #pragma unroll
            for (int mi = 0; mi < 4; ++mi) a[mi] = *(const bf16x8*)(ap + ((size_t)mi * 16) * 8);
            #pragma unroll
            for (int mi = 0; mi < 4; ++mi)
                #pragma unroll
                for (int ni = 0; ni < 4; ++ni)
                    co_[mi][ni] = __builtin_amdgcn_mfma_f32_16x16x32_bf16(a[mi], bo1[ni], co_[mi][ni], 0, 0, 0);
        }
    }

    // ---- epilogue: add selected bias, float2 full-density stores ----
    #pragma unroll
    for (int mi = 0; mi < 4; ++mi) {
        const int cob = coH * 128 + coQ * 64 + mi * 16 + q * 4;
        float bh[4], bl[4];
        #pragma unroll
        for (int r = 0; r < 4; ++r) { bh[r] = bH[cob + r]; bl[r] = bL[cob + r]; }
        #pragma unroll
        for (int r = 0; r < 4; ++r) {
            float* orow = out + (((size_t)b * COUT + cob + r) * HO + oy) * WO;
            #pragma unroll
            for (int ni = 0; ni < 4; ++ni) {
                const int x = ni * 16 + l15;
                float2 v;
                v.x = ce[mi][ni][r]  + (selE[ni] ? bh[r] : bl[r]);
                v.y = co_[mi][ni][r] + (selO[ni] ? bh[r] : bl[r]);
                *(float2*)(orow + 2 * x) = v;
            }
        }
    }
}

// ---------------------------------------------------------------------------
extern "C" void kernel_launch(void* const* d_in, const int* in_sizes, int n_in,
                              void* d_out, int out_size, void* d_ws, size_t ws_size,
                              hipStream_t stream) {
    const float* inx    = (const float*)d_in[0];
    const float* mask   = (const float*)d_in[1];
    // d_in[2] = inv_mask (unused: mask is exactly 0/1)
    const float* w_high = (const float*)d_in[3];
    const float* b_high = (const float*)d_in[4];
    const float* w_low1 = (const float*)d_in[5];
    const float* b_low1 = (const float*)d_in[6];
    const float* w_low2 = (const float*)d_in[7];
    const float* b_low2 = (const float*)d_in[8];
    float* out = (float*)d_out;

    char* ws = (char*)d_ws;
    u16* Xt  = (u16*)(ws);                 //  8,519,680 B
    u16* X2t = (u16*)(ws + 8519680);       //  2,129,920 B
    u16* WPH = (u16*)(ws + 10649600);      //  1,179,648 B
    u16* WPL = (u16*)(ws + 11829248);      //    294,912 B
    u16* W1P = (u16*)(ws + 12124160);      //     32,768 B  (total ~11.6 MiB)

    k_pack_w<<<72, 256, 0, stream>>>(w_high, w_low2, w_low1, WPH, WPL, W1P);
    k_prep<<<BATCH * 65, 256, 0, stream>>>(inx, W1P, b_low1, Xt, X2t);
    k_main<<<512, 256, 0, stream>>>(Xt, X2t, WPH, WPL, b_high, b_low2, mask, out);
}